// Round 7
// baseline (422.829 us; speedup 1.0000x reference)
//
#include <hip/hip_runtime.h>
#include <math.h>

// CentroidInstanceLoss: N=2M points, D=16, B=8 subbatches, M=32 labels.
// out = (L_pull + L_push)/B  (single fp32 scalar)
//
// R11: structural folding. R10 ledger: fill(harness,77us) + segsum 78 + pull
// (~70-90, never observed) + finalize(~20-40) + final + gaps = 272. Register-
// resident fusion is impossible (N*D*4B = 128MB = the whole chip's RF), so two
// passes stay. This round: (1) finalize folded into segsum via last-block-done
// (acq-rel agent counter; pp re-read through atomic-add-zero -> reads at the
// coherence point, immune to XCD-L2 staleness); (2) k_final folded into pull
// the same way; (3) pull rebuilt as the R8-proven staged gload_lds pipeline
// (no in-loop vmem ops -> clean vmcnt schedule) with mus stored TRANSPOSED
// [d][seg] so per-lane centroid reads are conflict-free ds_read_b32 (row-major
// was a 32-way bank conflict: lane segs consecutive -> same bank pair).

#define DD 16
#define MM 32
#define BBATCH 8
#define SEGS 256          // B*M
#define DELTA_V 0.5f
#define DELTA_D 1.5f
#define NEPS 1e-8f

#define NTHR 256
#define TILE_PTS 256                    // one point per thread per tile
#define TPB 8                           // tiles per chunk
#define CHUNK_PTS (TILE_PTS * TPB)      // 2048 points; canonical nchunks=1024
#define DEPTH 2                         // LDS double-buffer
#define KP 16                           // replicated global partials
#define MAXBLK 1024

// ws layout (floats):
#define PP_STRIDE ((DD + 1) * SEGS)     // 4352, copy stride, [d][seg]
#define OFF_PP    0
#define OFF_CTR   (KP * PP_STRIDE)      // int: segsum done-counter
#define OFF_CTR2  (OFF_CTR + 1)         // int: pull done-counter
#define OFF_ACC   (OFF_CTR + 4)         // pull partial accumulator
#define OFF_MUT   (OFF_CTR + 16)        // mus transposed [d][seg], 4096
#define OFF_INVW  (OFF_MUT + DD * SEGS) // 256
#define OFF_PUSH  (OFF_INVW + SEGS)
#define WS_ZERO_FLOATS (OFF_CTR + 16)   // zero pp + ctrs + acc

__device__ __forceinline__ void gload16(const void* g, void* l) {
    __builtin_amdgcn_global_load_lds(
        (const __attribute__((address_space(1))) void*)g,
        (__attribute__((address_space(3))) void*)l, 16, 0, 0);
}
__device__ __forceinline__ void gload4(const void* g, void* l) {
    __builtin_amdgcn_global_load_lds(
        (const __attribute__((address_space(1))) void*)g,
        (__attribute__((address_space(3))) void*)l, 4, 0, 0);
}

__device__ __forceinline__ void lds_fadd(float* p, float v) {
    __hip_atomic_fetch_add(p, v, __ATOMIC_RELAXED, __HIP_MEMORY_SCOPE_WORKGROUP);
}

__device__ __forceinline__ float block_reduce_sum(float v) {
    #pragma unroll
    for (int o = 32; o > 0; o >>= 1) v += __shfl_down(v, o, 64);
    __shared__ float red[4];
    int wid  = threadIdx.x >> 6;
    int lane = threadIdx.x & 63;
    if (lane == 0) red[wid] = v;
    __syncthreads();
    v = (threadIdx.x < (NTHR >> 6)) ? red[threadIdx.x] : 0.0f;
    if (wid == 0) {
        #pragma unroll
        for (int o = 32; o > 0; o >>= 1) v += __shfl_down(v, o, 64);
    }
    return v;  // valid on thread 0
}

// flush a full-point accumulator into transposed LDS planes [d][seg]
// (LDS atomics: lgkmcnt domain -- does NOT perturb the vmcnt pipeline)
__device__ __forceinline__ void flush_point(float* lsT, int seg,
                                            float4 a0, float4 a1,
                                            float4 a2, float4 a3, float cnt) {
    lds_fadd(&lsT[ 0*SEGS + seg], a0.x); lds_fadd(&lsT[ 1*SEGS + seg], a0.y);
    lds_fadd(&lsT[ 2*SEGS + seg], a0.z); lds_fadd(&lsT[ 3*SEGS + seg], a0.w);
    lds_fadd(&lsT[ 4*SEGS + seg], a1.x); lds_fadd(&lsT[ 5*SEGS + seg], a1.y);
    lds_fadd(&lsT[ 6*SEGS + seg], a1.z); lds_fadd(&lsT[ 7*SEGS + seg], a1.w);
    lds_fadd(&lsT[ 8*SEGS + seg], a2.x); lds_fadd(&lsT[ 9*SEGS + seg], a2.y);
    lds_fadd(&lsT[10*SEGS + seg], a2.z); lds_fadd(&lsT[11*SEGS + seg], a2.w);
    lds_fadd(&lsT[12*SEGS + seg], a3.x); lds_fadd(&lsT[13*SEGS + seg], a3.y);
    lds_fadd(&lsT[14*SEGS + seg], a3.z); lds_fadd(&lsT[15*SEGS + seg], a3.w);
    lds_fadd(&lsT[16*SEGS + seg], cnt);
}

// Stage one 256-point tile (wave-local): 4x 1KB data + labels + sub.
// LDS dest is linear (wave-uniform base + lane*size); the GLOBAL slot index
// carries the involution q ^ ((q>>3)&3) so reads can de-swizzle.
__device__ __forceinline__ void stage_tile(const float* gbase,
                                           const int* labels, const int* sub,
                                           float* db, int* lb, int* sb,
                                           int pb, int w, int lane) {
    const float* gs = gbase + (size_t)pb * DD;
    { int q = (w << 8) +   0 + lane;
      gload16(gs + (size_t)(q ^ ((q >> 3) & 3)) * 4, db + ((w << 8) +   0) * 4); }
    { int q = (w << 8) +  64 + lane;
      gload16(gs + (size_t)(q ^ ((q >> 3) & 3)) * 4, db + ((w << 8) +  64) * 4); }
    { int q = (w << 8) + 128 + lane;
      gload16(gs + (size_t)(q ^ ((q >> 3) & 3)) * 4, db + ((w << 8) + 128) * 4); }
    { int q = (w << 8) + 192 + lane;
      gload16(gs + (size_t)(q ^ ((q >> 3) & 3)) * 4, db + ((w << 8) + 192) * 4); }
    gload4(labels + pb + (w << 6) + lane, lb + (w << 6));
    gload4(sub    + pb + (w << 6) + lane, sb + (w << 6));
}

__global__ void __launch_bounds__(NTHR)
k_segsum(const float4* __restrict__ o4,
         const int* __restrict__ labels,
         const int* __restrict__ sub,
         float* __restrict__ wsf,
         int n) {
    __shared__ float lsT[(DD + 1) * SEGS];        // 17 KB
    __shared__ float dbuf[DEPTH][TILE_PTS * DD];  // 32 KB
    __shared__ int   labbuf[DEPTH][TILE_PTS];     // 2 KB
    __shared__ int   subbuf[DEPTH][TILE_PTS];
    __shared__ int   lastflag;
    for (int i = threadIdx.x; i < (DD + 1) * SEGS; i += NTHR) lsT[i] = 0.0f;
    __syncthreads();

    const int t    = threadIdx.x;
    const int w    = t >> 6;
    const int lane = t & 63;
    const int xm   = (t >> 1) & 3;   // read-side involution bits for this point
    const float* gbase = (const float*)o4;
    float* pp = wsf + OFF_PP;

    float4 c0 = {0,0,0,0}, c1 = {0,0,0,0}, c2 = {0,0,0,0}, c3 = {0,0,0,0};
    float cnt = 0.0f;
    int cur = -1;

    const int nchunks = n / CHUNK_PTS;
    for (int cb = blockIdx.x; cb < nchunks; cb += gridDim.x) {
        const int pbase = cb * CHUNK_PTS;
        stage_tile(gbase, labels, sub, &dbuf[0][0], &labbuf[0][0], &subbuf[0][0],
                   pbase + 0 * TILE_PTS, w, lane);
        stage_tile(gbase, labels, sub, &dbuf[1][0], &labbuf[1][0], &subbuf[1][0],
                   pbase + 1 * TILE_PTS, w, lane);
        #pragma unroll
        for (int ti = 0; ti < TPB; ++ti) {
            const int bi = ti & 1;
            if (ti < TPB - 1) asm volatile("s_waitcnt vmcnt(6)" ::: "memory");
            else              asm volatile("s_waitcnt vmcnt(0)" ::: "memory");
            int lb = labbuf[bi][t];
            int sv = subbuf[bi][t];
            const float* db = &dbuf[bi][0];
            float4 a = *(const float4*)&db[((4*t + 0) ^ xm) * 4];
            float4 b = *(const float4*)&db[((4*t + 1) ^ xm) * 4];
            float4 c = *(const float4*)&db[((4*t + 2) ^ xm) * 4];
            float4 e = *(const float4*)&db[((4*t + 3) ^ xm) * 4];
            int seg = sv * MM + lb;
            float ss = a.x*a.x + a.y*a.y + a.z*a.z + a.w*a.w
                     + b.x*b.x + b.y*b.y + b.z*b.z + b.w*b.w
                     + c.x*c.x + c.y*c.y + c.z*c.z + c.w*c.w
                     + e.x*e.x + e.y*e.y + e.z*e.z + e.w*e.w;
            float rn = 1.0f / (sqrtf(ss) + NEPS);
            if (seg != cur) {                  // never fires for canonical input
                if (cur >= 0) flush_point(lsT, cur, c0, c1, c2, c3, cnt);
                c0 = c1 = c2 = c3 = (float4){0,0,0,0};
                cnt = 0.0f;
                cur = seg;
            }
            c0.x = fmaf(a.x, rn, c0.x); c0.y = fmaf(a.y, rn, c0.y);
            c0.z = fmaf(a.z, rn, c0.z); c0.w = fmaf(a.w, rn, c0.w);
            c1.x = fmaf(b.x, rn, c1.x); c1.y = fmaf(b.y, rn, c1.y);
            c1.z = fmaf(b.z, rn, c1.z); c1.w = fmaf(b.w, rn, c1.w);
            c2.x = fmaf(c.x, rn, c2.x); c2.y = fmaf(c.y, rn, c2.y);
            c2.z = fmaf(c.z, rn, c2.z); c2.w = fmaf(c.w, rn, c2.w);
            c3.x = fmaf(e.x, rn, c3.x); c3.y = fmaf(e.y, rn, c3.y);
            c3.z = fmaf(e.z, rn, c3.z); c3.w = fmaf(e.w, rn, c3.w);
            cnt += 1.0f;
            __builtin_amdgcn_sched_barrier(0);   // keep re-stage after consume
            if (ti + 2 < TPB)
                stage_tile(gbase, labels, sub, &dbuf[bi][0], &labbuf[bi][0],
                           &subbuf[bi][0], pbase + (ti + 2) * TILE_PTS, w, lane);
        }
    }
    // tail points (non-canonical n only): simple direct-global path, block 0
    if (blockIdx.x == 0) {
        for (int p = nchunks * CHUNK_PTS + t; p < n; p += NTHR) {
            float4 a = o4[4*p+0], b = o4[4*p+1], c = o4[4*p+2], e = o4[4*p+3];
            int seg = sub[p] * MM + labels[p];
            float ss = a.x*a.x + a.y*a.y + a.z*a.z + a.w*a.w
                     + b.x*b.x + b.y*b.y + b.z*b.z + b.w*b.w
                     + c.x*c.x + c.y*c.y + c.z*c.z + c.w*c.w
                     + e.x*e.x + e.y*e.y + e.z*e.z + e.w*e.w;
            float rn = 1.0f / (sqrtf(ss) + NEPS);
            if (seg != cur) {
                if (cur >= 0) flush_point(lsT, cur, c0, c1, c2, c3, cnt);
                c0 = c1 = c2 = c3 = (float4){0,0,0,0};
                cnt = 0.0f;
                cur = seg;
            }
            c0.x = fmaf(a.x, rn, c0.x); c0.y = fmaf(a.y, rn, c0.y);
            c0.z = fmaf(a.z, rn, c0.z); c0.w = fmaf(a.w, rn, c0.w);
            c1.x = fmaf(b.x, rn, c1.x); c1.y = fmaf(b.y, rn, c1.y);
            c1.z = fmaf(b.z, rn, c1.z); c1.w = fmaf(b.w, rn, c1.w);
            c2.x = fmaf(c.x, rn, c2.x); c2.y = fmaf(c.y, rn, c2.y);
            c2.z = fmaf(c.z, rn, c2.z); c2.w = fmaf(c.w, rn, c2.w);
            c3.x = fmaf(e.x, rn, c3.x); c3.y = fmaf(e.y, rn, c3.y);
            c3.z = fmaf(e.z, rn, c3.z); c3.w = fmaf(e.w, rn, c3.w);
            cnt += 1.0f;
        }
    }
    if (cur >= 0) flush_point(lsT, cur, c0, c1, c2, c3, cnt);
    __syncthreads();

    // global flush (post-loop): transposed [d][seg], coalesced over s
    float* gdst = pp + (size_t)(blockIdx.x & (KP - 1)) * PP_STRIDE;
    for (int s = t; s < SEGS; s += NTHR) {
        float c = lsT[DD * SEGS + s];
        if (c != 0.0f) {
            #pragma unroll
            for (int d = 0; d < DD; ++d)
                unsafeAtomicAdd(&gdst[d * SEGS + s], lsT[d * SEGS + s]);
            unsafeAtomicAdd(&gdst[DD * SEGS + s], c);
        }
    }

    // ---- last-block-done finalize (replaces k_finalize_push) ----
    __threadfence();
    if (t == 0) {
        int* ctr = (int*)(wsf + OFF_CTR);
        int prev = __hip_atomic_fetch_add(ctr, 1, __ATOMIC_ACQ_REL,
                                          __HIP_MEMORY_SCOPE_AGENT);
        lastflag = (prev == (int)gridDim.x - 1) ? 1 : 0;
    }
    __syncthreads();
    if (lastflag) {
        // t == segment index. Read pp via atomic-add-zero: reads at the
        // coherence point, immune to stale L1/L2 across XCDs.
        float s17[DD + 1];
        #pragma unroll
        for (int d = 0; d <= DD; ++d) s17[d] = 0.0f;
        for (int k = 0; k < KP; ++k) {
            float* src = pp + (size_t)k * PP_STRIDE + t;
            #pragma unroll
            for (int d = 0; d <= DD; ++d)
                s17[d] += unsafeAtomicAdd(&src[d * SEGS], 0.0f);
        }
        float cnt2 = s17[DD];
        float ic   = (cnt2 > 0.0f) ? 1.0f / cnt2 : 0.0f;
        #pragma unroll
        for (int d = 0; d < DD; ++d) {
            float m = s17[d] * ic;
            wsf[OFF_MUT + d * SEGS + t] = m;   // transposed [d][seg]
            lsT[d * SEGS + t] = m;             // reuse lsT (partials dead)
        }
        wsf[OFF_INVW + t] = (cnt2 > 0.0f) ? 1.0f / ((float)MM * cnt2) : 0.0f;
        __syncthreads();

        int b = t >> 5, m1 = t & 31;
        float acc = 0.0f;
        for (int m2 = 0; m2 < MM; ++m2) {
            float pd = 0.0f;
            #pragma unroll
            for (int d = 0; d < DD; ++d)
                pd += fabsf(lsT[d * SEGS + b * MM + m1] - lsT[d * SEGS + b * MM + m2]);
            float h = 2.0f * DELTA_D - pd;
            if (m2 != m1 && h > 0.0f) acc += h * h;
        }
        float tot = block_reduce_sum(acc);
        if (t == 0) wsf[OFF_PUSH] = tot / (float)(MM * (MM - 1));
    }
}

__global__ void __launch_bounds__(NTHR)
k_pull(const float4* __restrict__ o4,
       const int* __restrict__ labels,
       const int* __restrict__ sub,
       float* __restrict__ wsf,
       int n) {
    __shared__ float muT[DD * SEGS];              // 16 KB, transposed [d][seg]
    __shared__ float siw[SEGS];                   // 1 KB
    __shared__ float dbuf[DEPTH][TILE_PTS * DD];  // 32 KB
    __shared__ int   labbuf[DEPTH][TILE_PTS];
    __shared__ int   subbuf[DEPTH][TILE_PTS];
    __shared__ int   lastflag;
    for (int i = threadIdx.x; i < DD * SEGS; i += NTHR) muT[i] = wsf[OFF_MUT + i];
    for (int i = threadIdx.x; i < SEGS; i += NTHR) siw[i] = wsf[OFF_INVW + i];
    __syncthreads();

    const int t    = threadIdx.x;
    const int w    = t >> 6;
    const int lane = t & 63;
    const int xm   = (t >> 1) & 3;
    const float* gbase = (const float*)o4;

    float acc = 0.0f;

    const int nchunks = n / CHUNK_PTS;
    for (int cb = blockIdx.x; cb < nchunks; cb += gridDim.x) {
        const int pbase = cb * CHUNK_PTS;
        stage_tile(gbase, labels, sub, &dbuf[0][0], &labbuf[0][0], &subbuf[0][0],
                   pbase + 0 * TILE_PTS, w, lane);
        stage_tile(gbase, labels, sub, &dbuf[1][0], &labbuf[1][0], &subbuf[1][0],
                   pbase + 1 * TILE_PTS, w, lane);
        #pragma unroll
        for (int ti = 0; ti < TPB; ++ti) {
            const int bi = ti & 1;
            if (ti < TPB - 1) asm volatile("s_waitcnt vmcnt(6)" ::: "memory");
            else              asm volatile("s_waitcnt vmcnt(0)" ::: "memory");
            int lb = labbuf[bi][t];
            int sv = subbuf[bi][t];
            const float* db = &dbuf[bi][0];
            float4 a = *(const float4*)&db[((4*t + 0) ^ xm) * 4];
            float4 b = *(const float4*)&db[((4*t + 1) ^ xm) * 4];
            float4 c = *(const float4*)&db[((4*t + 2) ^ xm) * 4];
            float4 e = *(const float4*)&db[((4*t + 3) ^ xm) * 4];
            int seg = sv * MM + lb;
            float ss = a.x*a.x + a.y*a.y + a.z*a.z + a.w*a.w
                     + b.x*b.x + b.y*b.y + b.z*b.z + b.w*b.w
                     + c.x*c.x + c.y*c.y + c.z*c.z + c.w*c.w
                     + e.x*e.x + e.y*e.y + e.z*e.z + e.w*e.w;
            float rn = 1.0f / (sqrtf(ss) + NEPS);
            // conflict-free ds_read_b32: consecutive lanes -> consecutive segs
            float dist;
            dist  = fabsf(muT[ 0*SEGS + seg] - a.x * rn)
                  + fabsf(muT[ 1*SEGS + seg] - a.y * rn)
                  + fabsf(muT[ 2*SEGS + seg] - a.z * rn)
                  + fabsf(muT[ 3*SEGS + seg] - a.w * rn);
            dist += fabsf(muT[ 4*SEGS + seg] - b.x * rn)
                  + fabsf(muT[ 5*SEGS + seg] - b.y * rn)
                  + fabsf(muT[ 6*SEGS + seg] - b.z * rn)
                  + fabsf(muT[ 7*SEGS + seg] - b.w * rn);
            dist += fabsf(muT[ 8*SEGS + seg] - c.x * rn)
                  + fabsf(muT[ 9*SEGS + seg] - c.y * rn)
                  + fabsf(muT[10*SEGS + seg] - c.z * rn)
                  + fabsf(muT[11*SEGS + seg] - c.w * rn);
            dist += fabsf(muT[12*SEGS + seg] - e.x * rn)
                  + fabsf(muT[13*SEGS + seg] - e.y * rn)
                  + fabsf(muT[14*SEGS + seg] - e.z * rn)
                  + fabsf(muT[15*SEGS + seg] - e.w * rn);
            float h = fmaxf(dist - DELTA_V, 0.0f);
            acc = fmaf(h * h, siw[seg], acc);
            __builtin_amdgcn_sched_barrier(0);
            if (ti + 2 < TPB)
                stage_tile(gbase, labels, sub, &dbuf[bi][0], &labbuf[bi][0],
                           &subbuf[bi][0], pbase + (ti + 2) * TILE_PTS, w, lane);
        }
    }
    // tail (non-canonical n only): direct path, block 0, global transposed mus
    if (blockIdx.x == 0) {
        for (int p = nchunks * CHUNK_PTS + t; p < n; p += NTHR) {
            float4 a = o4[4*p+0], b = o4[4*p+1], c = o4[4*p+2], e = o4[4*p+3];
            int seg = sub[p] * MM + labels[p];
            float ss = a.x*a.x + a.y*a.y + a.z*a.z + a.w*a.w
                     + b.x*b.x + b.y*b.y + b.z*b.z + b.w*b.w
                     + c.x*c.x + c.y*c.y + c.z*c.z + c.w*c.w
                     + e.x*e.x + e.y*e.y + e.z*e.z + e.w*e.w;
            float rn = 1.0f / (sqrtf(ss) + NEPS);
            float x[DD] = {a.x*rn,a.y*rn,a.z*rn,a.w*rn, b.x*rn,b.y*rn,b.z*rn,b.w*rn,
                           c.x*rn,c.y*rn,c.z*rn,c.w*rn, e.x*rn,e.y*rn,e.z*rn,e.w*rn};
            float dist = 0.0f;
            #pragma unroll
            for (int d = 0; d < DD; ++d)
                dist += fabsf(wsf[OFF_MUT + d * SEGS + seg] - x[d]);
            float h = fmaxf(dist - DELTA_V, 0.0f);
            acc = fmaf(h * h, wsf[OFF_INVW + seg], acc);
        }
    }
    float tot = block_reduce_sum(acc);
    if (t == 0) unsafeAtomicAdd(&wsf[OFF_ACC], tot);

    // ---- last-block-done final (replaces k_final) ----
    __threadfence();
    if (t == 0) {
        int* ctr2 = (int*)(wsf + OFF_CTR2);
        int prev = __hip_atomic_fetch_add(ctr2, 1, __ATOMIC_ACQ_REL,
                                          __HIP_MEMORY_SCOPE_AGENT);
        lastflag = (prev == (int)gridDim.x - 1) ? 1 : 0;
    }
    __syncthreads();
    if (lastflag && t == 0) {
        float pull = unsafeAtomicAdd(&wsf[OFF_ACC], 0.0f);  // coherent read
        float push = wsf[OFF_PUSH];
        // out pointer passed via wsf? no -- out is a kernel arg; see launch
    }
}

// tiny epilogue kernel is avoided by passing out to k_pull; redeclare with out:
__global__ void k_pull_out_writer(float* __restrict__ wsf, float* __restrict__ out);

extern "C" void kernel_launch(void* const* d_in, const int* in_sizes, int n_in,
                              void* d_out, int out_size, void* d_ws, size_t ws_size,
                              hipStream_t stream);

// -- k_pull needs the out pointer; simplest correct form: small writer kernel
__global__ void k_out(const float* __restrict__ wsf, float* __restrict__ out) {
    if (threadIdx.x == 0)
        out[0] = (wsf[OFF_ACC] + wsf[OFF_PUSH]) * (1.0f / (float)BBATCH);
}

extern "C" void kernel_launch(void* const* d_in, const int* in_sizes, int n_in,
                              void* d_out, int out_size, void* d_ws, size_t ws_size,
                              hipStream_t stream) {
    const float* outputs = (const float*)d_in[0];
    const int* labels    = (const int*)d_in[1];
    const int* sub       = (const int*)d_in[2];
    int n = in_sizes[0] / DD;

    float* wsf = (float*)d_ws;

    int nchunks = n / CHUNK_PTS;                  // 1024 for canonical N
    int nblk = nchunks < 1 ? 1 : (nchunks > MAXBLK ? MAXBLK : nchunks);

    hipMemsetAsync(d_ws, 0, (size_t)WS_ZERO_FLOATS * sizeof(float), stream);

    k_segsum<<<nblk, NTHR, 0, stream>>>((const float4*)outputs, labels, sub,
                                        wsf, n);
    k_pull<<<nblk, NTHR, 0, stream>>>((const float4*)outputs, labels, sub,
                                      wsf, n);
    k_out<<<1, 64, 0, stream>>>(wsf, (float*)d_out);
}

// Round 8
// 272.073 us; speedup vs baseline: 1.5541x; 1.5541x over previous
//
#include <hip/hip_runtime.h>
#include <math.h>

// CentroidInstanceLoss: N=2M points, D=16, B=8 subbatches, M=32 labels.
// out = (L_pull + L_push)/B  (single fp32 scalar)
//
// R12 = R10 (measured best, 272us) + ONE change: segsum pipeline DEPTH 2->3.
// R11 post-mortem: folding finalize pushed segsum LDS 54272->54784B, crossing
// the 3-blocks/CU cliff (54272*3=162816 <= 163840 < 54784*3) -> 175us. Reverted.
// R10 segsum: VALUBusy 6%, ~94% vmcnt-wait at 1.9 TB/s. Untried lever: per-wave
// MLP depth. DEPTH=3 keeps 18 loads in flight/wave (steady wait vmcnt(12),
// tail 12/6/0), LDS 71KB -> 2 blocks/CU (~= R10's effective residency), so
// wave count is held while in-flight rises 1.5x -- single-variable A/B.
// Hot loop stays vmem-free (R9 lesson: in-loop vmem atomics cost ~50us even
// when never executed). k_pull / finalize / final: R10 verbatim.

#define DD 16
#define MM 32
#define BBATCH 8
#define SEGS 256          // B*M
#define DELTA_V 0.5f
#define DELTA_D 1.5f
#define NEPS 1e-8f

#define NTHR 256
#define TILE_PTS 256                    // one point per thread per tile
#define TPB 8                           // tiles per chunk
#define CHUNK_PTS (TILE_PTS * TPB)      // 2048 points; canonical nchunks=1024
#define DEPTH 3                         // LDS triple-buffer (R12 change)
#define KP 32                           // replicated global partials
#define MAXBLK 2048                     // segsum grid cap
#define PULLBLK 4096                    // pull grid (and pull_part capacity)

// ws layout (floats):
//   [OFF_PP,   +KP*4352)  partials  [k][d][seg]  (d=16 is count plane)
//   [OFF_MUS,  +4096)     mus       [seg][16]  (seg-major)
//   [OFF_INVW, +256)      invw      [seg] = 1/(M*count)
//   [OFF_PUSH, +16)       push_acc
//   [OFF_PULL, +PULLBLK)  pull_part
#define OFF_PP    0
#define OFF_MUS   (KP * 4352)
#define OFF_INVW  (OFF_MUS + 4096)
#define OFF_PUSH  (OFF_INVW + 256)
#define OFF_PULL  (OFF_PUSH + 16)
#define WS_ZERO_FLOATS (KP * 4352)

__device__ __forceinline__ void gload16(const void* g, void* l) {
    __builtin_amdgcn_global_load_lds(
        (const __attribute__((address_space(1))) void*)g,
        (__attribute__((address_space(3))) void*)l, 16, 0, 0);
}
__device__ __forceinline__ void gload4(const void* g, void* l) {
    __builtin_amdgcn_global_load_lds(
        (const __attribute__((address_space(1))) void*)g,
        (__attribute__((address_space(3))) void*)l, 4, 0, 0);
}

__device__ __forceinline__ void lds_fadd(float* p, float v) {
    __hip_atomic_fetch_add(p, v, __ATOMIC_RELAXED, __HIP_MEMORY_SCOPE_WORKGROUP);
}

__device__ __forceinline__ float block_reduce_sum(float v) {
    #pragma unroll
    for (int o = 32; o > 0; o >>= 1) v += __shfl_down(v, o, 64);
    __shared__ float red[4];
    int wid  = threadIdx.x >> 6;
    int lane = threadIdx.x & 63;
    if (lane == 0) red[wid] = v;
    __syncthreads();
    v = (threadIdx.x < (NTHR >> 6)) ? red[threadIdx.x] : 0.0f;
    if (wid == 0) {
        #pragma unroll
        for (int o = 32; o > 0; o >>= 1) v += __shfl_down(v, o, 64);
    }
    return v;  // valid on thread 0
}

// flush a full-point accumulator into transposed LDS planes [d][seg]
// (LDS atomics: lgkmcnt domain -- does NOT perturb the vmcnt pipeline)
__device__ __forceinline__ void flush_point(float* lsT, int seg,
                                            float4 a0, float4 a1,
                                            float4 a2, float4 a3, float cnt) {
    lds_fadd(&lsT[ 0*SEGS + seg], a0.x); lds_fadd(&lsT[ 1*SEGS + seg], a0.y);
    lds_fadd(&lsT[ 2*SEGS + seg], a0.z); lds_fadd(&lsT[ 3*SEGS + seg], a0.w);
    lds_fadd(&lsT[ 4*SEGS + seg], a1.x); lds_fadd(&lsT[ 5*SEGS + seg], a1.y);
    lds_fadd(&lsT[ 6*SEGS + seg], a1.z); lds_fadd(&lsT[ 7*SEGS + seg], a1.w);
    lds_fadd(&lsT[ 8*SEGS + seg], a2.x); lds_fadd(&lsT[ 9*SEGS + seg], a2.y);
    lds_fadd(&lsT[10*SEGS + seg], a2.z); lds_fadd(&lsT[11*SEGS + seg], a2.w);
    lds_fadd(&lsT[12*SEGS + seg], a3.x); lds_fadd(&lsT[13*SEGS + seg], a3.y);
    lds_fadd(&lsT[14*SEGS + seg], a3.z); lds_fadd(&lsT[15*SEGS + seg], a3.w);
    lds_fadd(&lsT[16*SEGS + seg], cnt);
}

// Stage one 256-point tile (wave-local): 4x 1KB data + labels + sub.
// LDS dest is linear (HW: wave-uniform base + lane*size); the GLOBAL slot
// index carries the involution q ^ ((q>>3)&3) so reads can de-swizzle.
#define STAGE_TILE(bi_, pb_) do {                                              \
    const float* gs_ = (const float*)o4 + (size_t)(pb_) * DD;                  \
    { int q_ = (w << 8) +   0 + lane;                                          \
      gload16(gs_ + (size_t)(q_ ^ ((q_ >> 3) & 3)) * 4, &dbuf[bi_][((w << 8) +   0) * 4]); } \
    { int q_ = (w << 8) +  64 + lane;                                          \
      gload16(gs_ + (size_t)(q_ ^ ((q_ >> 3) & 3)) * 4, &dbuf[bi_][((w << 8) +  64) * 4]); } \
    { int q_ = (w << 8) + 128 + lane;                                          \
      gload16(gs_ + (size_t)(q_ ^ ((q_ >> 3) & 3)) * 4, &dbuf[bi_][((w << 8) + 128) * 4]); } \
    { int q_ = (w << 8) + 192 + lane;                                          \
      gload16(gs_ + (size_t)(q_ ^ ((q_ >> 3) & 3)) * 4, &dbuf[bi_][((w << 8) + 192) * 4]); } \
    gload4(labels + (pb_) + (w << 6) + lane, &labbuf[bi_][w << 6]);            \
    gload4(sub    + (pb_) + (w << 6) + lane, &subbuf[bi_][w << 6]);            \
} while (0)

__global__ void __launch_bounds__(NTHR)
k_segsum(const float4* __restrict__ o4,
         const int* __restrict__ labels,
         const int* __restrict__ sub,
         float* __restrict__ pp,
         int n) {
    __shared__ float lsT[(DD + 1) * SEGS];        // 17 KB
    __shared__ float dbuf[DEPTH][TILE_PTS * DD];  // 48 KB
    __shared__ int   labbuf[DEPTH][TILE_PTS];     // 3 KB
    __shared__ int   subbuf[DEPTH][TILE_PTS];     // 3 KB
    for (int i = threadIdx.x; i < (DD + 1) * SEGS; i += NTHR) lsT[i] = 0.0f;
    __syncthreads();

    const int t    = threadIdx.x;
    const int w    = t >> 6;
    const int lane = t & 63;
    const int xm   = (t >> 1) & 3;   // read-side involution bits for this point

    float4 c0 = {0,0,0,0}, c1 = {0,0,0,0}, c2 = {0,0,0,0}, c3 = {0,0,0,0};
    float cnt = 0.0f;
    int cur = -1;

    const int nchunks = n / CHUNK_PTS;
    for (int cb = blockIdx.x; cb < nchunks; cb += gridDim.x) {
        const int pbase = cb * CHUNK_PTS;
        STAGE_TILE(0, pbase + 0 * TILE_PTS);
        STAGE_TILE(1, pbase + 1 * TILE_PTS);
        STAGE_TILE(2, pbase + 2 * TILE_PTS);
        #pragma unroll
        for (int ti = 0; ti < TPB; ++ti) {
            const int bi = ti % 3;               // compile-time under unroll
            // drain exactly tile ti: allow 6 per tile still in flight
            if (ti < TPB - 2)      asm volatile("s_waitcnt vmcnt(12)" ::: "memory");
            else if (ti == TPB - 2) asm volatile("s_waitcnt vmcnt(6)" ::: "memory");
            else                    asm volatile("s_waitcnt vmcnt(0)" ::: "memory");
            int lb = labbuf[bi][t];
            int sv = subbuf[bi][t];
            const float* db = &dbuf[bi][0];
            float4 a = *(const float4*)&db[((4*t + 0) ^ xm) * 4];
            float4 b = *(const float4*)&db[((4*t + 1) ^ xm) * 4];
            float4 c = *(const float4*)&db[((4*t + 2) ^ xm) * 4];
            float4 e = *(const float4*)&db[((4*t + 3) ^ xm) * 4];
            int seg = sv * MM + lb;
            float ss = a.x*a.x + a.y*a.y + a.z*a.z + a.w*a.w
                     + b.x*b.x + b.y*b.y + b.z*b.z + b.w*b.w
                     + c.x*c.x + c.y*c.y + c.z*c.z + c.w*c.w
                     + e.x*e.x + e.y*e.y + e.z*e.z + e.w*e.w;
            float rn = 1.0f / (sqrtf(ss) + NEPS);
            if (seg != cur) {                  // never fires for canonical input
                if (cur >= 0) flush_point(lsT, cur, c0, c1, c2, c3, cnt);
                c0 = c1 = c2 = c3 = (float4){0,0,0,0};
                cnt = 0.0f;
                cur = seg;
            }
            c0.x = fmaf(a.x, rn, c0.x); c0.y = fmaf(a.y, rn, c0.y);
            c0.z = fmaf(a.z, rn, c0.z); c0.w = fmaf(a.w, rn, c0.w);
            c1.x = fmaf(b.x, rn, c1.x); c1.y = fmaf(b.y, rn, c1.y);
            c1.z = fmaf(b.z, rn, c1.z); c1.w = fmaf(b.w, rn, c1.w);
            c2.x = fmaf(c.x, rn, c2.x); c2.y = fmaf(c.y, rn, c2.y);
            c2.z = fmaf(c.z, rn, c2.z); c2.w = fmaf(c.w, rn, c2.w);
            c3.x = fmaf(e.x, rn, c3.x); c3.y = fmaf(e.y, rn, c3.y);
            c3.z = fmaf(e.z, rn, c3.z); c3.w = fmaf(e.w, rn, c3.w);
            cnt += 1.0f;
            __builtin_amdgcn_sched_barrier(0);   // keep re-stage after consume
            if (ti + 3 < TPB) STAGE_TILE(bi, pbase + (ti + 3) * TILE_PTS);
        }
    }
    // tail points (non-canonical n only): simple direct-global path, block 0
    if (blockIdx.x == 0) {
        for (int p = nchunks * CHUNK_PTS + t; p < n; p += NTHR) {
            float4 a = o4[4*p+0], b = o4[4*p+1], c = o4[4*p+2], e = o4[4*p+3];
            int seg = sub[p] * MM + labels[p];
            float ss = a.x*a.x + a.y*a.y + a.z*a.z + a.w*a.w
                     + b.x*b.x + b.y*b.y + b.z*b.z + b.w*b.w
                     + c.x*c.x + c.y*c.y + c.z*c.z + c.w*c.w
                     + e.x*e.x + e.y*e.y + e.z*e.z + e.w*e.w;
            float rn = 1.0f / (sqrtf(ss) + NEPS);
            if (seg != cur) {
                if (cur >= 0) flush_point(lsT, cur, c0, c1, c2, c3, cnt);
                c0 = c1 = c2 = c3 = (float4){0,0,0,0};
                cnt = 0.0f;
                cur = seg;
            }
            c0.x = fmaf(a.x, rn, c0.x); c0.y = fmaf(a.y, rn, c0.y);
            c0.z = fmaf(a.z, rn, c0.z); c0.w = fmaf(a.w, rn, c0.w);
            c1.x = fmaf(b.x, rn, c1.x); c1.y = fmaf(b.y, rn, c1.y);
            c1.z = fmaf(b.z, rn, c1.z); c1.w = fmaf(b.w, rn, c1.w);
            c2.x = fmaf(c.x, rn, c2.x); c2.y = fmaf(c.y, rn, c2.y);
            c2.z = fmaf(c.z, rn, c2.z); c2.w = fmaf(c.w, rn, c2.w);
            c3.x = fmaf(e.x, rn, c3.x); c3.y = fmaf(e.y, rn, c3.y);
            c3.z = fmaf(e.z, rn, c3.z); c3.w = fmaf(e.w, rn, c3.w);
            cnt += 1.0f;
        }
    }
    if (cur >= 0) flush_point(lsT, cur, c0, c1, c2, c3, cnt);
    __syncthreads();

    // global flush (post-loop, vmem atomics OK here): transposed [d][seg],
    // coalesced over s; only segments this block touched (count != 0)
    float* gdst = pp + (size_t)(blockIdx.x & (KP - 1)) * ((DD + 1) * SEGS);
    for (int s = t; s < SEGS; s += NTHR) {
        float c = lsT[DD * SEGS + s];
        if (c != 0.0f) {
            #pragma unroll
            for (int d = 0; d < DD; ++d)
                unsafeAtomicAdd(&gdst[d * SEGS + s], lsT[d * SEGS + s]);
            unsafeAtomicAdd(&gdst[DD * SEGS + s], c);
        }
    }
}

__global__ void k_finalize_push(float* __restrict__ ws) {
    const float* pp = ws + OFF_PP;
    float* mus  = ws + OFF_MUS;
    float* invw = ws + OFF_INVW;
    float* push = ws + OFF_PUSH;

    __shared__ float muT[DD * SEGS];
    int t = threadIdx.x;  // 256 threads == one per segment

    // reduce the KP partial copies; [k][d][seg] layout -> coalesced over t
    float s17[DD + 1];
    #pragma unroll
    for (int d = 0; d <= DD; ++d) s17[d] = 0.0f;
    #pragma unroll 2
    for (int k = 0; k < KP; ++k) {
        const float* src = pp + (size_t)k * ((DD + 1) * SEGS) + t;
        #pragma unroll
        for (int d = 0; d <= DD; ++d) s17[d] += src[d * SEGS];
    }
    float cnt = s17[DD];
    float ic  = (cnt > 0.0f) ? 1.0f / cnt : 0.0f;
    #pragma unroll
    for (int d = 0; d < DD; ++d) {
        float m = s17[d] * ic;
        mus[t * DD + d]   = m;
        muT[d * SEGS + t] = m;
    }
    invw[t] = (cnt > 0.0f) ? 1.0f / ((float)MM * cnt) : 0.0f;
    __syncthreads();

    int b = t >> 5, m1 = t & 31;
    float acc = 0.0f;
    for (int m2 = 0; m2 < MM; ++m2) {
        float pd = 0.0f;
        #pragma unroll
        for (int d = 0; d < DD; ++d)
            pd += fabsf(muT[d * SEGS + b * MM + m1] - muT[d * SEGS + b * MM + m2]);
        float h = 2.0f * DELTA_D - pd;
        if (m2 != m1 && h > 0.0f) acc += h * h;
    }
    float tot = block_reduce_sum(acc);
    if (t == 0) push[0] = tot / (float)(MM * (MM - 1));
}

__global__ void __launch_bounds__(NTHR, 6)
k_pull(const float4* __restrict__ o4,
       const int* __restrict__ labels,
       const int* __restrict__ sub,
       const float* __restrict__ mus,
       const float* __restrict__ invw,
       float* __restrict__ pull_part,
       int n) {
    __shared__ float muL[DD * SEGS];  // 16 KB, seg-major
    __shared__ float siw[SEGS];       // 1 KB
    for (int i = threadIdx.x; i < DD * SEGS; i += NTHR) muL[i] = mus[i];
    for (int i = threadIdx.x; i < SEGS; i += NTHR) siw[i] = invw[i];
    __syncthreads();

    float acc = 0.0f;
    const int stride = gridDim.x * NTHR;
    // branchless point-per-thread grid-stride: 2 rounds/thread canonically;
    // mu read unconditionally from LDS (wave-broadcast: neighbors share seg)
    #pragma unroll 2
    for (int p = blockIdx.x * NTHR + threadIdx.x; p < n; p += stride) {
        int seg = sub[p] * MM + labels[p];
        float4 a = o4[4*p+0], b = o4[4*p+1], c = o4[4*p+2], e = o4[4*p+3];
        float ss = a.x*a.x + a.y*a.y + a.z*a.z + a.w*a.w
                 + b.x*b.x + b.y*b.y + b.z*b.z + b.w*b.w
                 + c.x*c.x + c.y*c.y + c.z*c.z + c.w*c.w
                 + e.x*e.x + e.y*e.y + e.z*e.z + e.w*e.w;
        float rn = 1.0f / (sqrtf(ss) + NEPS);
        const float* mu = &muL[seg * DD];
        float4 m0 = *(const float4*)&mu[ 0];
        float4 m1 = *(const float4*)&mu[ 4];
        float4 m2 = *(const float4*)&mu[ 8];
        float4 m3 = *(const float4*)&mu[12];
        float dist;
        dist  = fabsf(m0.x - a.x * rn) + fabsf(m0.y - a.y * rn)
              + fabsf(m0.z - a.z * rn) + fabsf(m0.w - a.w * rn);
        dist += fabsf(m1.x - b.x * rn) + fabsf(m1.y - b.y * rn)
              + fabsf(m1.z - b.z * rn) + fabsf(m1.w - b.w * rn);
        dist += fabsf(m2.x - c.x * rn) + fabsf(m2.y - c.y * rn)
              + fabsf(m2.z - c.z * rn) + fabsf(m2.w - c.w * rn);
        dist += fabsf(m3.x - e.x * rn) + fabsf(m3.y - e.y * rn)
              + fabsf(m3.z - e.z * rn) + fabsf(m3.w - e.w * rn);
        float h = fmaxf(dist - DELTA_V, 0.0f);
        acc = fmaf(h * h, siw[seg], acc);
    }
    float tot = block_reduce_sum(acc);
    if (threadIdx.x == 0) pull_part[blockIdx.x] = tot;
}

__global__ void k_final(const float* __restrict__ ws, float* __restrict__ out,
                        int nblk) {
    const float* push      = ws + OFF_PUSH;
    const float* pull_part = ws + OFF_PULL;
    int t = threadIdx.x;
    float v = 0.0f;
    for (int k = t; k < nblk; k += NTHR) v += pull_part[k];
    float tot = block_reduce_sum(v);
    if (t == 0) out[0] = (tot + push[0]) * (1.0f / (float)BBATCH);
}

extern "C" void kernel_launch(void* const* d_in, const int* in_sizes, int n_in,
                              void* d_out, int out_size, void* d_ws, size_t ws_size,
                              hipStream_t stream) {
    const float* outputs = (const float*)d_in[0];
    const int* labels    = (const int*)d_in[1];
    const int* sub       = (const int*)d_in[2];
    int n = in_sizes[0] / DD;

    float* ws        = (float*)d_ws;
    float* pp        = ws + OFF_PP;
    float* mus       = ws + OFF_MUS;
    float* invw      = ws + OFF_INVW;
    float* pull_part = ws + OFF_PULL;

    int nchunks = n / CHUNK_PTS;                  // 1024 for canonical N
    int nblk = nchunks < 1 ? 1 : (nchunks > MAXBLK ? MAXBLK : nchunks);

    long npb = ((long)n + NTHR - 1) / NTHR;
    int nblk2 = npb < 1 ? 1 : (npb > PULLBLK ? PULLBLK : (int)npb);  // 4096

    hipMemsetAsync(d_ws, 0, (size_t)WS_ZERO_FLOATS * sizeof(float), stream);

    k_segsum<<<nblk, NTHR, 0, stream>>>((const float4*)outputs, labels, sub,
                                        pp, n);
    k_finalize_push<<<1, NTHR, 0, stream>>>(ws);
    k_pull<<<nblk2, NTHR, 0, stream>>>((const float4*)outputs, labels, sub,
                                       mus, invw, pull_part, n);
    k_final<<<1, NTHR, 0, stream>>>(ws, (float*)d_out, nblk2);
}